// Round 2
// baseline (365.112 us; speedup 1.0000x reference)
//
#include <hip/hip_runtime.h>
#include <cstdint>

// Problem constants: B=2, S=2048, E=2048, H=16, D=128
#define S_LEN 2048
#define EMB   2048
#define NHEAD 16
#define HDIM  128
#define MROWS 4096   // B*S
#define NQKV  6144   // 3*E

typedef __bf16 bf16x8 __attribute__((ext_vector_type(8)));
typedef __bf16 bf16x4 __attribute__((ext_vector_type(4)));
typedef float  f32x4  __attribute__((ext_vector_type(4)));

#define MFMA16(a, b, c) __builtin_amdgcn_mfma_f32_16x16x32_bf16((a), (b), (c), 0, 0, 0)

__device__ __forceinline__ unsigned short f2bf(float f) {
  unsigned u = __builtin_bit_cast(unsigned, f);
  u += 0x7fffu + ((u >> 16) & 1u);   // RNE
  return (unsigned short)(u >> 16);
}
__device__ __forceinline__ float bf2f(unsigned short u) {
  unsigned v = ((unsigned)u) << 16;
  return __builtin_bit_cast(float, v);
}

// async global->LDS, 16B per lane. LDS dest must be wave-uniform base + lane*16.
__device__ __forceinline__ void gl_lds16(const unsigned short* g, unsigned short* l) {
  __builtin_amdgcn_global_load_lds(
      (const __attribute__((address_space(1))) void*)(uintptr_t)g,
      (__attribute__((address_space(3))) void*)(unsigned int)(uintptr_t)l,
      16, 0, 0);
}

// ---------------- cast fp32 -> bf16 (contiguous) ----------------
__global__ void cast_bf16(const float* __restrict__ in, unsigned short* __restrict__ out, int n) {
  int i = (blockIdx.x * 256 + threadIdx.x) * 4;
  if (i >= n) return;
  float4 v = *(const float4*)(in + i);
  ushort4 o;
  o.x = f2bf(v.x); o.y = f2bf(v.y); o.z = f2bf(v.z); o.w = f2bf(v.w);
  *(ushort4*)(out + i) = o;
}

// ---------------- transpose + cast: in[R][C] fp32 -> out[C][R] bf16 ----------------
__global__ void transpose_cast(const float* __restrict__ in, unsigned short* __restrict__ out,
                               int R, int C) {
  __shared__ float tile[32][33];
  int bx = blockIdx.x << 5;  // along C
  int by = blockIdx.y << 5;  // along R
  int tx = threadIdx.x, ty = threadIdx.y;
  for (int j = 0; j < 32; j += 8)
    tile[ty + j][tx] = in[(size_t)(by + ty + j) * C + bx + tx];
  __syncthreads();
  for (int j = 0; j < 32; j += 8)
    out[(size_t)(bx + ty + j) * R + by + tx] = f2bf(tile[tx][ty + j]);
}

// ---------------- GEMM1: QKV projection, 8-phase-style pipelined 256x192 tile ----------------
// BM=256 BN=192 BK=64, 512 threads = 8 waves as 2M x 4N; per-wave C = 128x48
// (rows interleaved across A-halves: frag r<4 -> rows [gm*64 + r*16) in half0,
//  r>=4 -> 128 + gm*64 + (r-4)*16 in half1). 48 MFMA : 22 ds_read_b128 per K-tile.
// LDS 112KB dynamic: A dbuf 2x[256][64], B dbuf 2x[192][64], XOR-swizzle granule 8.
// 3 phases/K-tile: {vmcnt(N) counted, barrier, stage-issue next piece, ds_read, 16 MFMA}.
// Stage order per tile: B0,B1,B2 (ph0), A0a,A0b (ph1), A1a,A1b (ph2).
// Waits: ph0 vmcnt(2) forces B(t)+A0(t), leaves A1(t) in flight;
//        ph1 vmcnt(3) forces A1(t), leaves B(t+1) in flight. Never 0 until t=31.
__global__ __launch_bounds__(512, 2) void gemm_qkv8(const unsigned short* __restrict__ A,
                                                    const unsigned short* __restrict__ Bt,
                                                    unsigned short* __restrict__ Qo,
                                                    unsigned short* __restrict__ Ko,
                                                    unsigned short* __restrict__ Vt) {
  extern __shared__ unsigned short lds[];
  unsigned short* Abuf = lds;           // [2][256*64] = 32768 shorts
  unsigned short* Bbuf = lds + 32768;   // [2][192*64] = 24576 shorts

  const int tid = threadIdx.x, w = tid >> 6, lane = tid & 63;
  const int fr = lane & 15, g = lane >> 4;
  const int gm = w >> 2, gn = w & 3;
  const int srow = tid >> 3, jp = tid & 7;

  // grid: 16 mt x 32 nt = 512 blocks; XCD-chunked (512%8==0 -> bijective),
  // nt-fastest so concurrent blocks on an XCD share the A panel (L2-resident).
  const int bid = blockIdx.x;
  const int wg = (bid & 7) * 64 + (bid >> 3);
  const int mt = wg >> 5, nt = wg & 31;
  const int m0 = mt << 8;
  const int n0 = nt * 192;

  auto issueB = [&](int buf, int kk, int third) {  // third in 0..2, 64 rows each
    const int row = (third << 6) + srow;
    gl_lds16(Bt + (size_t)(n0 + row) * 2048 + kk + ((jp ^ (row & 7)) << 3),
             Bbuf + buf * 12288 + (row << 6) + (jp << 3));
  };
  auto issueA = [&](int buf, int kk, int q) {      // q in 0..3, 64 rows each
    const int row = (q << 6) + srow;
    gl_lds16(A + (size_t)(m0 + row) * 2048 + kk + ((jp ^ (row & 7)) << 3),
             Abuf + buf * 16384 + (row << 6) + (jp << 3));
  };

  f32x4 acc[8][3] = {};
  bf16x8 alo[4][2], ahi[4][2], bv[2][2], bc2[2];

  // prologue: tile 0, exact steady-state issue order
  issueB(0, 0, 0); issueB(0, 0, 1); issueB(0, 0, 2);
  issueA(0, 0, 0); issueA(0, 0, 1); issueA(0, 0, 2); issueA(0, 0, 3);

  for (int t = 0; t < 32; ++t) {
    const int cb = t & 1, nb = cb ^ 1;
    const unsigned short* Ab = Abuf + cb * 16384;
    const unsigned short* Bb = Bbuf + cb * 12288;
    const int kn = (t + 1) << 6;

    // ================= phase 0: Q0 = r0-3 x c0-1 =================
    asm volatile("s_waitcnt vmcnt(2)" ::: "memory");   // B(t)+A0(t) landed
    asm volatile("" ::: "memory");
    __builtin_amdgcn_s_barrier();
    asm volatile("" ::: "memory");
    if (t < 31) { issueB(nb, kn, 0); issueB(nb, kn, 1); issueB(nb, kn, 2); }
#pragma unroll
    for (int r = 0; r < 4; ++r)
#pragma unroll
      for (int ks = 0; ks < 2; ++ks)
        alo[r][ks] = *(const bf16x8*)(Ab + ((gm * 64 + r * 16 + fr) << 6) +
                                      ((((ks << 2) + g) ^ (fr & 7)) << 3));
#pragma unroll
    for (int c = 0; c < 2; ++c)
#pragma unroll
      for (int ks = 0; ks < 2; ++ks)
        bv[c][ks] = *(const bf16x8*)(Bb + ((gn * 48 + c * 16 + fr) << 6) +
                                     ((((ks << 2) + g) ^ (fr & 7)) << 3));
    __builtin_amdgcn_s_setprio(1);
#pragma unroll
    for (int ks = 0; ks < 2; ++ks)
#pragma unroll
      for (int r = 0; r < 4; ++r)
#pragma unroll
        for (int c = 0; c < 2; ++c)
          acc[r][c] = MFMA16(alo[r][ks], bv[c][ks], acc[r][c]);
    __builtin_amdgcn_s_setprio(0);

    // ================= phase 1: Q1 = (r0-3 + r4-7) x c2 =================
    if (t < 31) { asm volatile("s_waitcnt vmcnt(3)" ::: "memory"); }  // A1(t) landed
    else        { asm volatile("s_waitcnt vmcnt(0)" ::: "memory"); }
    asm volatile("" ::: "memory");
    __builtin_amdgcn_s_barrier();
    asm volatile("" ::: "memory");
    if (t < 31) { issueA(nb, kn, 0); issueA(nb, kn, 1); }
#pragma unroll
    for (int ks = 0; ks < 2; ++ks)
      bc2[ks] = *(const bf16x8*)(Bb + ((gn * 48 + 32 + fr) << 6) +
                                 ((((ks << 2) + g) ^ (fr & 7)) << 3));
    __builtin_amdgcn_s_setprio(1);
#pragma unroll
    for (int ks = 0; ks < 2; ++ks)
#pragma unroll
      for (int r = 0; r < 4; ++r)
        acc[r][2] = MFMA16(alo[r][ks], bc2[ks], acc[r][2]);
    __builtin_amdgcn_s_setprio(0);
#pragma unroll
    for (int r = 0; r < 4; ++r)
#pragma unroll
      for (int ks = 0; ks < 2; ++ks)
        ahi[r][ks] = *(const bf16x8*)(Ab + ((128 + gm * 64 + r * 16 + fr) << 6) +
                                      ((((ks << 2) + g) ^ (fr & 7)) << 3));
    __builtin_amdgcn_s_setprio(1);
#pragma unroll
    for (int ks = 0; ks < 2; ++ks)
#pragma unroll
      for (int r = 0; r < 4; ++r)
        acc[4 + r][2] = MFMA16(ahi[r][ks], bc2[ks], acc[4 + r][2]);
    __builtin_amdgcn_s_setprio(0);

    // ================= phase 2: Q2 = r4-7 x c0-1 =================
    asm volatile("" ::: "memory");
    __builtin_amdgcn_s_barrier();
    asm volatile("" ::: "memory");
    if (t < 31) { issueA(nb, kn, 2); issueA(nb, kn, 3); }
#pragma unroll
    for (int c = 0; c < 2; ++c)
#pragma unroll
      for (int ks = 0; ks < 2; ++ks)
        bv[c][ks] = *(const bf16x8*)(Bb + ((gn * 48 + c * 16 + fr) << 6) +
                                     ((((ks << 2) + g) ^ (fr & 7)) << 3));
    __builtin_amdgcn_s_setprio(1);
#pragma unroll
    for (int ks = 0; ks < 2; ++ks)
#pragma unroll
      for (int r = 0; r < 4; ++r)
#pragma unroll
        for (int c = 0; c < 2; ++c)
          acc[4 + r][c] = MFMA16(ahi[r][ks], bv[c][ks], acc[4 + r][c]);
    __builtin_amdgcn_s_setprio(0);
  }

  // ---------------- epilogue: scatter to Q / K / Vt ----------------
  // row(r, reg) = m0 + (r>>2)*128 + gm*64 + (r&3)*16 + g*4 + reg
  // col(c, fr)  = n0 + gn*48 + c*16 + fr   (16 | head size, so head uniform per frag)
  const int rowb = m0 & (S_LEN - 1);           // 256-tiles never cross the batch boundary
  const int bbase = (m0 >> 11) * NHEAD;
  for (int r = 0; r < 8; ++r) {
    const int sl = rowb + ((r >> 2) << 7) + (gm << 6) + ((r & 3) << 4) + (g << 2);
    for (int c = 0; c < 3; ++c) {
      const int ncol = n0 + gn * 48 + c * 16;
      const int which = ncol >> 11;            // 0=Q 1=K 2=V (varies within 192-wide tiles)
      const int h = (ncol >> 7) & 15;
      const int d = (ncol & 127) + fr;
      const int bh = bbase + h;
      if (which == 2) {
        ushort4 pk;
        pk.x = f2bf(acc[r][c][0]); pk.y = f2bf(acc[r][c][1]);
        pk.z = f2bf(acc[r][c][2]); pk.w = f2bf(acc[r][c][3]);
        *(ushort4*)(Vt + ((size_t)bh * HDIM + d) * S_LEN + sl) = pk;
      } else {
        unsigned short* dst = which ? Ko : Qo;
        for (int q4 = 0; q4 < 4; ++q4)
          dst[((size_t)bh * S_LEN + sl + q4) * HDIM + d] = f2bf(acc[r][c][q4]);
      }
    }
  }
}

// ---------------- Flash attention, split-K + swizzled LDS, FIXED-MAX softmax ----------------
// (unchanged verified version)
__global__ __launch_bounds__(256, 3) void attn(const unsigned short* __restrict__ Qg,
                                               const unsigned short* __restrict__ Kg,
                                               const unsigned short* __restrict__ Vtg,
                                               unsigned short* __restrict__ ctx,
                                               unsigned short* __restrict__ Opart,
                                               float* __restrict__ Lp) {
  __shared__ __align__(16) unsigned short SA[16384];  // 32KB: Qs alias Ks(16KB)+Vs(16KB)
  __shared__ __align__(16) unsigned short Ps[8192];   // 16KB C-layout-flat
  unsigned short* Qs = SA;
  unsigned short* Ks = SA;
  unsigned short* Vs = SA + 8192;

  const int blk = blockIdx.x;
  const int bh = blk & 31;
  const int t = blk >> 5;
  int qt, kt0, nkt, part;
  if (t < 8)       { qt = t;     kt0 = 0;  nkt = 2 * t + 2;       part = -1; }
  else if (t < 16) { qt = t;     kt0 = 0;  nkt = 16;              part = (bh << 3) + (qt - 8); }
  else             { qt = t - 8; kt0 = 16; nkt = 2 * qt - 14;     part = 256 + (bh << 3) + (qt - 8); }

  const int tid = threadIdx.x, wave = tid >> 6, lane = tid & 63;
  const int fr = lane & 15, g = lane >> 4;

  // stage Q tile [128][128], swizzled
  const unsigned short* qsrc = Qg + ((size_t)bh * S_LEN + (qt << 7)) * HDIM;
  for (int i = 0; i < 8; ++i) {
    int s0 = (i * 256 + tid) << 3;
    int q = s0 >> 7, jp = (s0 >> 3) & 15;
    gl_lds16(qsrc + (q << 7) + ((jp ^ (q & 15)) << 3), Qs + s0);
  }
  __builtin_amdgcn_s_waitcnt(0);
  __syncthreads();

  bf16x8 qf[2][4];
  for (int nbq = 0; nbq < 2; ++nbq)
    for (int kd = 0; kd < 4; ++kd) {
      int q = (wave << 5) + (nbq << 4) + fr;
      qf[nbq][kd] = *(const bf16x8*)(Qs + (q << 7) + ((((kd << 2) + g) ^ fr) << 3));
    }
  __syncthreads();  // Qs dead; SA becomes Ks/Vs

  float lsum[2] = {0.f, 0.f};  // per-lane partial of l (reduced in epilogue)
  f32x4 oacc[2][8] = {};
  const float scale = 0.08838834764831845f;  // 1/sqrt(128)

  const unsigned short* kbase = Kg + (size_t)bh * S_LEN * HDIM;
  const unsigned short* vbase = Vtg + (size_t)bh * HDIM * S_LEN;

  for (int kti = 0; kti < nkt; ++kti) {
    const int kt = kt0 + kti;
    // stage Ks[64][128] + Vs[128][64], swizzled
    const unsigned short* ks = kbase + ((size_t)kt << 6) * HDIM;
    const unsigned short* vs = vbase + (kt << 6);
    for (int i = 0; i < 4; ++i) {
      int s0 = (i * 256 + tid) << 3;
      int key = s0 >> 7, jk = (s0 >> 3) & 15;
      gl_lds16(ks + (key << 7) + ((jk ^ (key & 15)) << 3), Ks + s0);
      int d = s0 >> 6, jv = (s0 >> 3) & 7;
      gl_lds16(vs + (size_t)d * S_LEN + ((jv ^ (d & 7)) << 3), Vs + s0);
    }
    __builtin_amdgcn_s_waitcnt(0);
    __syncthreads();

    // S^T = K Q^T
    f32x4 sacc[2][4] = {};
    for (int kd = 0; kd < 4; ++kd)
      for (int kb = 0; kb < 4; ++kb) {
        bf16x8 kf = *(const bf16x8*)(Ks + (((kb << 4) + fr) << 7) + ((((kd << 2) + g) ^ fr) << 3));
        sacc[0][kb] = MFMA16(kf, qf[0][kd], sacc[0][kb]);
        sacc[1][kb] = MFMA16(kf, qf[1][kd], sacc[1][kb]);
      }

    // p = exp(s*scale), mask to 0 on diagonal tiles; accumulate per-lane l partials
    const bool diag = (kt >= 2 * qt);
    for (int nbq = 0; nbq < 2; ++nbq) {
      const int qg = (qt << 7) + (wave << 5) + (nbq << 4) + fr;
      float sum = 0.f;
      for (int kb = 0; kb < 4; ++kb) {
        float p[4];
        for (int r = 0; r < 4; ++r) {
          float v = sacc[nbq][kb][r] * scale;
          if (diag) {
            int keyg = (kt << 6) + (kb << 4) + (g << 2) + r;
            if (keyg > qg) v = -__builtin_inff();
          }
          p[r] = __expf(v);
          sum += p[r];
        }
        ushort4 pk;
        pk.x = f2bf(p[0]); pk.y = f2bf(p[1]);
        pk.z = f2bf(p[2]); pk.w = f2bf(p[3]);
        // C-layout-flat: [wave][nbq][kb][lane*4]
        *(ushort4*)(Ps + (((wave << 3) + (nbq << 2) + kb) << 8) + (lane << 2)) = pk;
      }
      lsum[nbq] += sum;
    }

    __builtin_amdgcn_s_waitcnt(0);  // drain Ps ds_writes before A-frag reads

    // O += P V
    for (int kc = 0; kc < 2; ++kc) {
      const int kbr = (kc << 1) + (g >> 1);
      bf16x8 ap[2];
      for (int h2 = 0; h2 < 2; ++h2) {
        const unsigned short* pb =
            Ps + (((wave << 3) + (h2 << 2) + kbr) << 8) + ((g & 1) << 7) + (fr << 2);
        bf16x4 a0 = *(const bf16x4*)pb;
        bf16x4 a1 = *(const bf16x4*)(pb + 64);
        bf16x8 a;
        a[0] = a0[0]; a[1] = a0[1]; a[2] = a0[2]; a[3] = a0[3];
        a[4] = a1[0]; a[5] = a1[1]; a[6] = a1[2]; a[7] = a1[3];
        ap[h2] = a;
      }
      for (int nd = 0; nd < 8; ++nd) {
        bf16x8 bv = *(const bf16x8*)(Vs + (((nd << 4) + fr) << 6) + ((((kc << 2) + g) ^ (fr & 7)) << 3));
        oacc[0][nd] = MFMA16(ap[0], bv, oacc[0][nd]);
        oacc[1][nd] = MFMA16(ap[1], bv, oacc[1][nd]);
      }
    }
    __syncthreads();  // all waves done with Ks/Vs before next stage
  }

  // reduce l partials across the 4 key-groups (once, not per-iter)
  for (int nbq = 0; nbq < 2; ++nbq) {
    lsum[nbq] += __shfl_xor(lsum[nbq], 16);
    lsum[nbq] += __shfl_xor(lsum[nbq], 32);
  }

  if (part < 0) {
    // full row: normalize + write ctx[b][s][h*128+d]
    const int b = bh >> 4, h = bh & 15;
    for (int mq = 0; mq < 2; ++mq)
      for (int r = 0; r < 4; ++r) {
        float lv = __shfl(lsum[mq], (lane & 48) | ((g << 2) + r));
        const float il = 1.0f / lv;
        const int s = (qt << 7) + (wave << 5) + (mq << 4) + (g << 2) + r;
        unsigned short* dst = ctx + ((size_t)(b * S_LEN + s) * EMB) + (h << 7);
        for (int nd = 0; nd < 8; ++nd)
          dst[(nd << 4) + fr] = f2bf(oacc[mq][nd][r] * il);
      }
  } else {
    // partial: unnormalized O' (bf16) + l (fp32)
    unsigned short* Ob = Opart + ((size_t)part << 14);
    for (int mq = 0; mq < 2; ++mq)
      for (int r = 0; r < 4; ++r) {
        const int ql = (wave << 5) + (mq << 4) + (g << 2) + r;
        unsigned short* dst = Ob + (ql << 7);
        for (int nd = 0; nd < 8; ++nd)
          dst[(nd << 4) + fr] = f2bf(oacc[mq][nd][r]);
      }
    if (g == 0)
      for (int nbq = 0; nbq < 2; ++nbq) {
        const int ql = (wave << 5) + (nbq << 4) + fr;
        Lp[(part << 7) + ql] = lsum[nbq];
      }
  }
}

// ---------------- combine partials for qt in [8,16) ----------------
__global__ void attn_combine(const unsigned short* __restrict__ Op,
                             const float* __restrict__ Lp,
                             unsigned short* __restrict__ ctx) {
  const int tid = threadIdx.x;
  const int rid = blockIdx.x * 16 + (tid >> 4);  // 0..32767
  const int l16 = tid & 15;
  const int bh = rid >> 10;
  const int qtl = (rid >> 7) & 7;
  const int ql = rid & 127;
  const int p = (bh << 3) + qtl;
  const float lA = Lp[(p << 7) + ql];
  const float lB = Lp[((256 + p) << 7) + ql];
  const float il = 1.0f / (lA + lB);
  const int d0 = l16 << 3;
  const unsigned short* a = Op + ((size_t)p << 14) + (ql << 7) + d0;
  const unsigned short* b = Op + ((size_t)(256 + p) << 14) + (ql << 7) + d0;
  const int bb = bh >> 4, h = bh & 15;
  const int s = ((qtl + 8) << 7) + ql;
  unsigned short* dst = ctx + ((size_t)(bb * S_LEN + s) * EMB) + (h << 7) + d0;
  ushort4 va0 = *(const ushort4*)a, va1 = *(const ushort4*)(a + 4);
  ushort4 vb0 = *(const ushort4*)b, vb1 = *(const ushort4*)(b + 4);
  ushort4 o0, o1;
  o0.x = f2bf((bf2f(va0.x) + bf2f(vb0.x)) * il);
  o0.y = f2bf((bf2f(va0.y) + bf2f(vb0.y)) * il);
  o0.z = f2bf((bf2f(va0.z) + bf2f(vb0.z)) * il);
  o0.w = f2bf((bf2f(va0.w) + bf2f(vb0.w)) * il);
  o1.x = f2bf((bf2f(va1.x) + bf2f(vb1.x)) * il);
  o1.y = f2bf((bf2f(va1.y) + bf2f(vb1.y)) * il);
  o1.z = f2bf((bf2f(va1.z) + bf2f(vb1.z)) * il);
  o1.w = f2bf((bf2f(va1.w) + bf2f(vb1.w)) * il);
  *(ushort4*)dst = o0;
  *(ushort4*)(dst + 4) = o1;
}

// ---------------- GEMM2: out[4096][2048] fp32 = ctx @ woutT^T ----------------
// Round-0 verified 128x128 kernel (3 blocks/CU TLP structure).
__global__ __launch_bounds__(256, 3) void gemm_out(const unsigned short* __restrict__ A,
                                                   const unsigned short* __restrict__ Bt,
                                                   float* __restrict__ C) {
  __shared__ __align__(16) unsigned short As[128 * 64];
  __shared__ __align__(16) unsigned short Bs[128 * 64];
  const int tid = threadIdx.x;
  const int n0 = blockIdx.x << 7;
  const int m0 = blockIdx.y << 7;
  const int wave = tid >> 6, lane = tid & 63;
  const int wm = (wave & 1) << 6, wn = (wave >> 1) << 6;
  const int fr = lane & 15, g = lane >> 4;
  const int q = tid >> 3;
  const int jp = tid & 7;
  f32x4 acc[4][4] = {};
  for (int k0 = 0; k0 < 2048; k0 += 64) {
    for (int i = 0; i < 4; ++i) {
      const int row = q + (i << 5);
      const int jsw = (jp ^ (row & 7)) << 3;
      gl_lds16(A + (size_t)(m0 + row) * 2048 + k0 + jsw, As + (row << 6) + (jp << 3));
      gl_lds16(Bt + (size_t)(n0 + row) * 2048 + k0 + jsw, Bs + (row << 6) + (jp << 3));
    }
    __builtin_amdgcn_s_waitcnt(0);
    __syncthreads();
    for (int ks = 0; ks < 2; ++ks) {
      const int slot = (((ks << 2) + g) ^ (fr & 7)) << 3;
      bf16x8 af[4], bfv[4];
      for (int i = 0; i < 4; ++i) af[i]  = *(const bf16x8*)(As + ((wm + (i << 4) + fr) << 6) + slot);
      for (int j = 0; j < 4; ++j) bfv[j] = *(const bf16x8*)(Bs + ((wn + (j << 4) + fr) << 6) + slot);
      for (int i = 0; i < 4; ++i)
        for (int j = 0; j < 4; ++j)
          acc[i][j] = MFMA16(af[i], bfv[j], acc[i][j]);
    }
    __syncthreads();
  }
  for (int i = 0; i < 4; ++i) {
    const int row = m0 + wm + (i << 4) + (g << 2);
    for (int j = 0; j < 4; ++j) {
      const int col = n0 + wn + (j << 4) + fr;
      for (int r = 0; r < 4; ++r)
        C[(size_t)(row + r) * EMB + col] = acc[i][j][r];
    }
  }
}

extern "C" void kernel_launch(void* const* d_in, const int* in_sizes, int n_in,
                              void* d_out, int out_size, void* d_ws, size_t ws_size,
                              hipStream_t stream) {
  const float* x    = (const float*)d_in[0];
  const float* wqkv = (const float*)d_in[1];
  const float* wout = (const float*)d_in[2];
  float* out = (float*)d_out;

  unsigned short* ws = (unsigned short*)d_ws;
  const size_t NELEM = (size_t)MROWS * EMB;            // 8388608
  unsigned short* xb    = ws;                          // reused as ctx
  unsigned short* wqkvT = xb + NELEM;                  // [6144][2048]; dead after gemm_qkv
  unsigned short* woutT = wqkvT + (size_t)NQKV * EMB;  // [2048][2048]
  unsigned short* Q     = woutT + (size_t)EMB * EMB;   // [32][2048][128]
  unsigned short* K     = Q + NELEM;
  unsigned short* Vt    = K + NELEM;                   // [32][128][2048]
  unsigned short* ctx   = xb;                          // alias: xb dead after gemm_qkv
  unsigned short* Opart = wqkvT;                       // alias: 512*16384 = 8.39M shorts
  float* Lp = (float*)(Opart + ((size_t)512 << 14));   // in wqkvT spare (12.58M region)

  // allow 112KB dynamic LDS for the pipelined QKV GEMM (one-time host setup)
  static bool attr_done = false;
  if (!attr_done) {
    (void)hipFuncSetAttribute((const void*)gemm_qkv8,
                              hipFuncAttributeMaxDynamicSharedMemorySize, 114688);
    attr_done = true;
  }

  cast_bf16<<<8192, 256, 0, stream>>>(x, xb, (int)NELEM);
  transpose_cast<<<dim3(NQKV / 32, EMB / 32), dim3(32, 8), 0, stream>>>(wqkv, wqkvT, EMB, NQKV);
  transpose_cast<<<dim3(EMB / 32, EMB / 32), dim3(32, 8), 0, stream>>>(wout, woutT, EMB, EMB);
  gemm_qkv8<<<512, 512, 114688, stream>>>(xb, wqkvT, Q, K, Vt);
  attn<<<768, 256, 0, stream>>>(Q, K, Vt, ctx, Opart, Lp);
  attn_combine<<<2048, 256, 0, stream>>>(Opart, Lp, ctx);
  gemm_out<<<dim3(EMB / 128, MROWS / 128), 256, 0, stream>>>(ctx, woutT, out);
}

// Round 3
// 362.636 us; speedup vs baseline: 1.0068x; 1.0068x over previous
//
#include <hip/hip_runtime.h>
#include <cstdint>

// Problem constants: B=2, S=2048, E=2048, H=16, D=128
#define S_LEN 2048
#define EMB   2048
#define NHEAD 16
#define HDIM  128
#define MROWS 4096   // B*S
#define NQKV  6144   // 3*E

typedef __bf16 bf16x8 __attribute__((ext_vector_type(8)));
typedef __bf16 bf16x4 __attribute__((ext_vector_type(4)));
typedef float  f32x4  __attribute__((ext_vector_type(4)));

#define MFMA16(a, b, c) __builtin_amdgcn_mfma_f32_16x16x32_bf16((a), (b), (c), 0, 0, 0)

__device__ __forceinline__ unsigned short f2bf(float f) {
  unsigned u = __builtin_bit_cast(unsigned, f);
  u += 0x7fffu + ((u >> 16) & 1u);   // RNE
  return (unsigned short)(u >> 16);
}
__device__ __forceinline__ float bf2f(unsigned short u) {
  unsigned v = ((unsigned)u) << 16;
  return __builtin_bit_cast(float, v);
}

// async global->LDS, 16B per lane. LDS dest must be wave-uniform base + lane*16.
__device__ __forceinline__ void gl_lds16(const unsigned short* g, unsigned short* l) {
  __builtin_amdgcn_global_load_lds(
      (const __attribute__((address_space(1))) void*)(uintptr_t)g,
      (__attribute__((address_space(3))) void*)(unsigned int)(uintptr_t)l,
      16, 0, 0);
}

#define FENCE() asm volatile("" ::: "memory")
#define BARRIER() do { FENCE(); __builtin_amdgcn_s_barrier(); FENCE(); } while (0)

// ---------------- cast fp32 -> bf16 (contiguous) ----------------
__global__ void cast_bf16(const float* __restrict__ in, unsigned short* __restrict__ out, int n) {
  int i = (blockIdx.x * 256 + threadIdx.x) * 4;
  if (i >= n) return;
  float4 v = *(const float4*)(in + i);
  ushort4 o;
  o.x = f2bf(v.x); o.y = f2bf(v.y); o.z = f2bf(v.z); o.w = f2bf(v.w);
  *(ushort4*)(out + i) = o;
}

// ---------------- transpose + cast: in[R][C] fp32 -> out[C][R] bf16 ----------------
__global__ void transpose_cast(const float* __restrict__ in, unsigned short* __restrict__ out,
                               int R, int C) {
  __shared__ float tile[32][33];
  int bx = blockIdx.x << 5;  // along C
  int by = blockIdx.y << 5;  // along R
  int tx = threadIdx.x, ty = threadIdx.y;
  for (int j = 0; j < 32; j += 8)
    tile[ty + j][tx] = in[(size_t)(by + ty + j) * C + bx + tx];
  __syncthreads();
  for (int j = 0; j < 32; j += 8)
    out[(size_t)(bx + ty + j) * R + by + tx] = f2bf(tile[tx][ty + j]);
}

// =================== m201-cadence pipelined GEMM core ===================
// BM=128, BN=128*NCOL, BK=64, 512 threads = 8 waves, wave w owns cols [w*16*NCOL, +16*NCOL).
// All waves read all 128 A-rows; per-wave C = 128 x 16*NCOL = acc[8][NCOL] f32x4.
// LDS dbuf: A 2x[128][64], B 2x[BN][64]; XOR-swizzle granule 8 (write src pre-swizzled,
// read slot ^= fr&7) -> conflict-free ds_read_b128 (verified structure, round-0).
// 4 phases per K-tile t, each: {ds_read frags; issue gl_lds per schedule; [vmcnt]; barrier;
// setprio(1); 2*NCOL*2 MFMA; setprio(0)}. Issue schedule for tile tau (BISS=2*NCOL B + 2 A):
//   B0,B1  at (tau-2, P3)  -> active buf B-region (last read 3 phases earlier: safe)
//   B2..B4 at (tau-1, P0), B5(+A0,A1) at (tau-1, P1)  -> idle buf
// Single counted wait per K-tile: vmcnt(2) at P3 (leaves only tau+2's B0,B1 in flight).
// Reads of a phase are valid at issue (staged a full tile earlier) -> barriers only enforce
// write-after-read region discipline; MFMA hoisting across barriers is benign.
template<int NCOL>
__device__ __forceinline__ void gemm_pipe2(const unsigned short* __restrict__ Ap,
                                           const unsigned short* __restrict__ Bp,
                                           int m0, int n0, f32x4 (&acc)[8][NCOL]) {
  constexpr int BN = 128 * NCOL;
  constexpr int BISS = 2 * NCOL;         // B gl_lds issues per K-tile (A adds 2 more)
  constexpr int NT = 32;                 // K=2048 / BK=64
  extern __shared__ unsigned short lds[];
  unsigned short* Abuf = lds;            // [2][128*64] shorts
  unsigned short* Bbuf = lds + 16384;    // [2][BN*64] shorts

  const int tid = threadIdx.x, w = tid >> 6, lane = tid & 63;
  const int fr = lane & 15, g = lane >> 4;
  const int srow = tid >> 3, jp = tid & 7;

  auto issueA = [&](int buf, int kk, int idx) {
    const int row = (idx << 6) + srow;
    gl_lds16(Ap + (size_t)(m0 + row) * 2048 + kk + ((jp ^ (row & 7)) << 3),
             Abuf + (buf << 13) + (row << 6) + (jp << 3));
  };
  auto issueB = [&](int buf, int kk, int idx) {
    const int row = (idx << 6) + srow;
    gl_lds16(Bp + (size_t)(n0 + row) * 2048 + kk + ((jp ^ (row & 7)) << 3),
             Bbuf + buf * (BN * 64) + (row << 6) + (jp << 3));
  };

  // prologue: tile0 fully + tile1's B0,B1; counted wait (2 in flight), matching steady state
#pragma unroll
  for (int i = 0; i < BISS; ++i) issueB(0, 0, i);
  issueA(0, 0, 0); issueA(0, 0, 1);
  issueB(1, 64, 0); issueB(1, 64, 1);
  asm volatile("s_waitcnt vmcnt(2)" ::: "memory");
  __builtin_amdgcn_s_barrier();
  FENCE();

  bf16x8 bfr[NCOL][2];
  for (int t = 0; t < NT; ++t) {
    const int cb = t & 1, nb = cb ^ 1;
    const unsigned short* Ab = Abuf + (cb << 13);
    const unsigned short* Bb = Bbuf + cb * (BN * 64);
    const int kn = (t + 1) << 6;
    const bool s1 = (t + 1 < NT), s2 = (t + 2 < NT);

    bf16x8 af[2][2];
    // ================= P0: rows 0-1, all B cols =================
#pragma unroll
    for (int c = 0; c < NCOL; ++c)
#pragma unroll
      for (int ks = 0; ks < 2; ++ks)
        bfr[c][ks] = *(const bf16x8*)(Bb + ((w * 16 * NCOL + c * 16 + fr) << 6) +
                                      ((((ks << 2) + g) ^ (fr & 7)) << 3));
#pragma unroll
    for (int rr = 0; rr < 2; ++rr)
#pragma unroll
      for (int ks = 0; ks < 2; ++ks)
        af[rr][ks] = *(const bf16x8*)(Ab + (((rr * 16) + fr) << 6) +
                                      ((((ks << 2) + g) ^ (fr & 7)) << 3));
    if (s1) {
      issueB(nb, kn, 2); issueB(nb, kn, 3);
      if (NCOL == 3) issueB(nb, kn, 4);
    }
    BARRIER();
    __builtin_amdgcn_s_setprio(1);
#pragma unroll
    for (int ks = 0; ks < 2; ++ks)
#pragma unroll
      for (int rr = 0; rr < 2; ++rr)
#pragma unroll
        for (int c = 0; c < NCOL; ++c)
          acc[rr][c] = MFMA16(af[rr][ks], bfr[c][ks], acc[rr][c]);
    __builtin_amdgcn_s_setprio(0);

    // ================= P1: rows 2-3 =================
#pragma unroll
    for (int rr = 0; rr < 2; ++rr)
#pragma unroll
      for (int ks = 0; ks < 2; ++ks)
        af[rr][ks] = *(const bf16x8*)(Ab + (((32 + rr * 16) + fr) << 6) +
                                      ((((ks << 2) + g) ^ (fr & 7)) << 3));
    if (s1) {
      if (NCOL == 3) issueB(nb, kn, 5);
      issueA(nb, kn, 0); issueA(nb, kn, 1);
    }
    BARRIER();
    __builtin_amdgcn_s_setprio(1);
#pragma unroll
    for (int ks = 0; ks < 2; ++ks)
#pragma unroll
      for (int rr = 0; rr < 2; ++rr)
#pragma unroll
        for (int c = 0; c < NCOL; ++c)
          acc[2 + rr][c] = MFMA16(af[rr][ks], bfr[c][ks], acc[2 + rr][c]);
    __builtin_amdgcn_s_setprio(0);

    // ================= P2: rows 4-5 =================
#pragma unroll
    for (int rr = 0; rr < 2; ++rr)
#pragma unroll
      for (int ks = 0; ks < 2; ++ks)
        af[rr][ks] = *(const bf16x8*)(Ab + (((64 + rr * 16) + fr) << 6) +
                                      ((((ks << 2) + g) ^ (fr & 7)) << 3));
    BARRIER();
    __builtin_amdgcn_s_setprio(1);
#pragma unroll
    for (int ks = 0; ks < 2; ++ks)
#pragma unroll
      for (int rr = 0; rr < 2; ++rr)
#pragma unroll
        for (int c = 0; c < NCOL; ++c)
          acc[4 + rr][c] = MFMA16(af[rr][ks], bfr[c][ks], acc[4 + rr][c]);
    __builtin_amdgcn_s_setprio(0);

    // ================= P3: rows 6-7, issue tau+2's B0,B1, counted vmcnt =================
#pragma unroll
    for (int rr = 0; rr < 2; ++rr)
#pragma unroll
      for (int ks = 0; ks < 2; ++ks)
        af[rr][ks] = *(const bf16x8*)(Ab + (((96 + rr * 16) + fr) << 6) +
                                      ((((ks << 2) + g) ^ (fr & 7)) << 3));
    if (s2) {
      const int kn2 = (t + 2) << 6;
      issueB(cb, kn2, 0); issueB(cb, kn2, 1);   // into active buf's B-region (reads done at P0)
      asm volatile("s_waitcnt vmcnt(2)" ::: "memory");  // tile t+1 fully landed
    } else if (s1) {
      asm volatile("s_waitcnt vmcnt(0)" ::: "memory");  // final boundary drain
    }
    BARRIER();
    __builtin_amdgcn_s_setprio(1);
#pragma unroll
    for (int ks = 0; ks < 2; ++ks)
#pragma unroll
      for (int rr = 0; rr < 2; ++rr)
#pragma unroll
        for (int c = 0; c < NCOL; ++c)
          acc[6 + rr][c] = MFMA16(af[rr][ks], bfr[c][ks], acc[6 + rr][c]);
    __builtin_amdgcn_s_setprio(0);
  }
}

// ---------------- GEMM1: QKV projection ----------------
// grid 512 = 32 mt x 16 nt; XCD-chunked, mt-fastest within chunk so the ~32
// concurrent blocks of an XCD share one B panel (1.5MB, L2-resident).
__global__ __launch_bounds__(512, 2) void gemm_qkv9(const unsigned short* __restrict__ A,
                                                    const unsigned short* __restrict__ Bt,
                                                    unsigned short* __restrict__ Qo,
                                                    unsigned short* __restrict__ Ko,
                                                    unsigned short* __restrict__ Vt) {
  const int bid = blockIdx.x;
  const int wg = (bid & 7) * 64 + (bid >> 3);
  const int mt = wg & 31, nt = wg >> 5;
  const int m0 = mt << 7, n0 = nt * 384;
  f32x4 acc[8][3] = {};
  gemm_pipe2<3>(A, Bt, m0, n0, acc);

  const int tid = threadIdx.x, w = tid >> 6, lane = tid & 63;
  const int fr = lane & 15, g = lane >> 4;
  const int rowb = m0 & (S_LEN - 1);
  const int bbase = (m0 >> 11) * NHEAD;
  for (int r = 0; r < 8; ++r) {
    const int sl = rowb + r * 16 + (g << 2);
    for (int c = 0; c < 3; ++c) {
      const int ncol = n0 + w * 48 + c * 16;
      const int which = ncol >> 11;            // 0=Q 1=K 2=V
      const int h = (ncol >> 7) & 15;
      const int d = (ncol & 127) + fr;
      const int bh = bbase + h;
      if (which == 2) {
        ushort4 pk;
        pk.x = f2bf(acc[r][c][0]); pk.y = f2bf(acc[r][c][1]);
        pk.z = f2bf(acc[r][c][2]); pk.w = f2bf(acc[r][c][3]);
        *(ushort4*)(Vt + ((size_t)bh * HDIM + d) * S_LEN + sl) = pk;
      } else {
        unsigned short* dst = which ? Ko : Qo;
        for (int q4 = 0; q4 < 4; ++q4)
          dst[((size_t)bh * S_LEN + sl + q4) * HDIM + d] = f2bf(acc[r][c][q4]);
      }
    }
  }
}

// ---------------- GEMM2: out = ctx @ woutT^T (fp32 out) ----------------
// grid 256 = 32 mt x 8 nt -> exactly 1 round; per-XCD one nt (1MB B panel).
__global__ __launch_bounds__(512, 2) void gemm_out9(const unsigned short* __restrict__ A,
                                                    const unsigned short* __restrict__ Bt,
                                                    float* __restrict__ C) {
  const int bid = blockIdx.x;
  const int wg = (bid & 7) * 32 + (bid >> 3);
  const int mt = wg & 31, nt = wg >> 5;
  const int m0 = mt << 7, n0 = nt << 8;
  f32x4 acc[8][2] = {};
  gemm_pipe2<2>(A, Bt, m0, n0, acc);

  const int tid = threadIdx.x, w = tid >> 6, lane = tid & 63;
  const int fr = lane & 15, g = lane >> 4;
  for (int r = 0; r < 8; ++r) {
    const int row = m0 + r * 16 + (g << 2);
    for (int c = 0; c < 2; ++c) {
      const int col = n0 + w * 32 + c * 16 + fr;
      for (int q4 = 0; q4 < 4; ++q4)
        C[(size_t)(row + q4) * EMB + col] = acc[r][c][q4];
    }
  }
}

// ---------------- Flash attention, split-K + swizzled LDS, FIXED-MAX softmax ----------------
// (unchanged verified version)
__global__ __launch_bounds__(256, 3) void attn(const unsigned short* __restrict__ Qg,
                                               const unsigned short* __restrict__ Kg,
                                               const unsigned short* __restrict__ Vtg,
                                               unsigned short* __restrict__ ctx,
                                               unsigned short* __restrict__ Opart,
                                               float* __restrict__ Lp) {
  __shared__ __align__(16) unsigned short SA[16384];  // 32KB: Qs alias Ks(16KB)+Vs(16KB)
  __shared__ __align__(16) unsigned short Ps[8192];   // 16KB C-layout-flat
  unsigned short* Qs = SA;
  unsigned short* Ks = SA;
  unsigned short* Vs = SA + 8192;

  const int blk = blockIdx.x;
  const int bh = blk & 31;
  const int t = blk >> 5;
  int qt, kt0, nkt, part;
  if (t < 8)       { qt = t;     kt0 = 0;  nkt = 2 * t + 2;       part = -1; }
  else if (t < 16) { qt = t;     kt0 = 0;  nkt = 16;              part = (bh << 3) + (qt - 8); }
  else             { qt = t - 8; kt0 = 16; nkt = 2 * qt - 14;     part = 256 + (bh << 3) + (qt - 8); }

  const int tid = threadIdx.x, wave = tid >> 6, lane = tid & 63;
  const int fr = lane & 15, g = lane >> 4;

  // stage Q tile [128][128], swizzled
  const unsigned short* qsrc = Qg + ((size_t)bh * S_LEN + (qt << 7)) * HDIM;
  for (int i = 0; i < 8; ++i) {
    int s0 = (i * 256 + tid) << 3;
    int q = s0 >> 7, jp = (s0 >> 3) & 15;
    gl_lds16(qsrc + (q << 7) + ((jp ^ (q & 15)) << 3), Qs + s0);
  }
  __builtin_amdgcn_s_waitcnt(0);
  __syncthreads();

  bf16x8 qf[2][4];
  for (int nbq = 0; nbq < 2; ++nbq)
    for (int kd = 0; kd < 4; ++kd) {
      int q = (wave << 5) + (nbq << 4) + fr;
      qf[nbq][kd] = *(const bf16x8*)(Qs + (q << 7) + ((((kd << 2) + g) ^ fr) << 3));
    }
  __syncthreads();  // Qs dead; SA becomes Ks/Vs

  float lsum[2] = {0.f, 0.f};  // per-lane partial of l (reduced in epilogue)
  f32x4 oacc[2][8] = {};
  const float scale = 0.08838834764831845f;  // 1/sqrt(128)

  const unsigned short* kbase = Kg + (size_t)bh * S_LEN * HDIM;
  const unsigned short* vbase = Vtg + (size_t)bh * HDIM * S_LEN;

  for (int kti = 0; kti < nkt; ++kti) {
    const int kt = kt0 + kti;
    // stage Ks[64][128] + Vs[128][64], swizzled
    const unsigned short* ks = kbase + ((size_t)kt << 6) * HDIM;
    const unsigned short* vs = vbase + (kt << 6);
    for (int i = 0; i < 4; ++i) {
      int s0 = (i * 256 + tid) << 3;
      int key = s0 >> 7, jk = (s0 >> 3) & 15;
      gl_lds16(ks + (key << 7) + ((jk ^ (key & 15)) << 3), Ks + s0);
      int d = s0 >> 6, jv = (s0 >> 3) & 7;
      gl_lds16(vs + (size_t)d * S_LEN + ((jv ^ (d & 7)) << 3), Vs + s0);
    }
    __builtin_amdgcn_s_waitcnt(0);
    __syncthreads();

    // S^T = K Q^T
    f32x4 sacc[2][4] = {};
    for (int kd = 0; kd < 4; ++kd)
      for (int kb = 0; kb < 4; ++kb) {
        bf16x8 kf = *(const bf16x8*)(Ks + (((kb << 4) + fr) << 7) + ((((kd << 2) + g) ^ fr) << 3));
        sacc[0][kb] = MFMA16(kf, qf[0][kd], sacc[0][kb]);
        sacc[1][kb] = MFMA16(kf, qf[1][kd], sacc[1][kb]);
      }

    // p = exp(s*scale), mask to 0 on diagonal tiles; accumulate per-lane l partials
    const bool diag = (kt >= 2 * qt);
    for (int nbq = 0; nbq < 2; ++nbq) {
      const int qg = (qt << 7) + (wave << 5) + (nbq << 4) + fr;
      float sum = 0.f;
      for (int kb = 0; kb < 4; ++kb) {
        float p[4];
        for (int r = 0; r < 4; ++r) {
          float v = sacc[nbq][kb][r] * scale;
          if (diag) {
            int keyg = (kt << 6) + (kb << 4) + (g << 2) + r;
            if (keyg > qg) v = -__builtin_inff();
          }
          p[r] = __expf(v);
          sum += p[r];
        }
        ushort4 pk;
        pk.x = f2bf(p[0]); pk.y = f2bf(p[1]);
        pk.z = f2bf(p[2]); pk.w = f2bf(p[3]);
        // C-layout-flat: [wave][nbq][kb][lane*4]
        *(ushort4*)(Ps + (((wave << 3) + (nbq << 2) + kb) << 8) + (lane << 2)) = pk;
      }
      lsum[nbq] += sum;
    }

    __builtin_amdgcn_s_waitcnt(0);  // drain Ps ds_writes before A-frag reads

    // O += P V
    for (int kc = 0; kc < 2; ++kc) {
      const int kbr = (kc << 1) + (g >> 1);
      bf16x8 ap[2];
      for (int h2 = 0; h2 < 2; ++h2) {
        const unsigned short* pb =
            Ps + (((wave << 3) + (h2 << 2) + kbr) << 8) + ((g & 1) << 7) + (fr << 2);
        bf16x4 a0 = *(const bf16x4*)pb;
        bf16x4 a1 = *(const bf16x4*)(pb + 64);
        bf16x8 a;
        a[0] = a0[0]; a[1] = a0[1]; a[2] = a0[2]; a[3] = a0[3];
        a[4] = a1[0]; a[5] = a1[1]; a[6] = a1[2]; a[7] = a1[3];
        ap[h2] = a;
      }
      for (int nd = 0; nd < 8; ++nd) {
        bf16x8 bv = *(const bf16x8*)(Vs + (((nd << 4) + fr) << 6) + ((((kc << 2) + g) ^ (fr & 7)) << 3));
        oacc[0][nd] = MFMA16(ap[0], bv, oacc[0][nd]);
        oacc[1][nd] = MFMA16(ap[1], bv, oacc[1][nd]);
      }
    }
    __syncthreads();  // all waves done with Ks/Vs before next stage
  }

  // reduce l partials across the 4 key-groups (once, not per-iter)
  for (int nbq = 0; nbq < 2; ++nbq) {
    lsum[nbq] += __shfl_xor(lsum[nbq], 16);
    lsum[nbq] += __shfl_xor(lsum[nbq], 32);
  }

  if (part < 0) {
    // full row: normalize + write ctx[b][s][h*128+d]
    const int b = bh >> 4, h = bh & 15;
    for (int mq = 0; mq < 2; ++mq)
      for (int r = 0; r < 4; ++r) {
        float lv = __shfl(lsum[mq], (lane & 48) | ((g << 2) + r));
        const float il = 1.0f / lv;
        const int s = (qt << 7) + (wave << 5) + (mq << 4) + (g << 2) + r;
        unsigned short* dst = ctx + ((size_t)(b * S_LEN + s) * EMB) + (h << 7);
        for (int nd = 0; nd < 8; ++nd)
          dst[(nd << 4) + fr] = f2bf(oacc[mq][nd][r] * il);
      }
  } else {
    // partial: unnormalized O' (bf16) + l (fp32)
    unsigned short* Ob = Opart + ((size_t)part << 14);
    for (int mq = 0; mq < 2; ++mq)
      for (int r = 0; r < 4; ++r) {
        const int ql = (wave << 5) + (mq << 4) + (g << 2) + r;
        unsigned short* dst = Ob + (ql << 7);
        for (int nd = 0; nd < 8; ++nd)
          dst[(nd << 4) + fr] = f2bf(oacc[mq][nd][r]);
      }
    if (g == 0)
      for (int nbq = 0; nbq < 2; ++nbq) {
        const int ql = (wave << 5) + (nbq << 4) + fr;
        Lp[(part << 7) + ql] = lsum[nbq];
      }
  }
}

// ---------------- combine partials for qt in [8,16) ----------------
__global__ void attn_combine(const unsigned short* __restrict__ Op,
                             const float* __restrict__ Lp,
                             unsigned short* __restrict__ ctx) {
  const int tid = threadIdx.x;
  const int rid = blockIdx.x * 16 + (tid >> 4);  // 0..32767
  const int l16 = tid & 15;
  const int bh = rid >> 10;
  const int qtl = (rid >> 7) & 7;
  const int ql = rid & 127;
  const int p = (bh << 3) + qtl;
  const float lA = Lp[(p << 7) + ql];
  const float lB = Lp[((256 + p) << 7) + ql];
  const float il = 1.0f / (lA + lB);
  const int d0 = l16 << 3;
  const unsigned short* a = Op + ((size_t)p << 14) + (ql << 7) + d0;
  const unsigned short* b = Op + ((size_t)(256 + p) << 14) + (ql << 7) + d0;
  const int bb = bh >> 4, h = bh & 15;
  const int s = ((qtl + 8) << 7) + ql;
  unsigned short* dst = ctx + ((size_t)(bb * S_LEN + s) * EMB) + (h << 7) + d0;
  ushort4 va0 = *(const ushort4*)a, va1 = *(const ushort4*)(a + 4);
  ushort4 vb0 = *(const ushort4*)b, vb1 = *(const ushort4*)(b + 4);
  ushort4 o0, o1;
  o0.x = f2bf((bf2f(va0.x) + bf2f(vb0.x)) * il);
  o0.y = f2bf((bf2f(va0.y) + bf2f(vb0.y)) * il);
  o0.z = f2bf((bf2f(va0.z) + bf2f(vb0.z)) * il);
  o0.w = f2bf((bf2f(va0.w) + bf2f(vb0.w)) * il);
  o1.x = f2bf((bf2f(va1.x) + bf2f(vb1.x)) * il);
  o1.y = f2bf((bf2f(va1.y) + bf2f(vb1.y)) * il);
  o1.z = f2bf((bf2f(va1.z) + bf2f(vb1.z)) * il);
  o1.w = f2bf((bf2f(va1.w) + bf2f(vb1.w)) * il);
  *(ushort4*)dst = o0;
  *(ushort4*)(dst + 4) = o1;
}

extern "C" void kernel_launch(void* const* d_in, const int* in_sizes, int n_in,
                              void* d_out, int out_size, void* d_ws, size_t ws_size,
                              hipStream_t stream) {
  const float* x    = (const float*)d_in[0];
  const float* wqkv = (const float*)d_in[1];
  const float* wout = (const float*)d_in[2];
  float* out = (float*)d_out;

  unsigned short* ws = (unsigned short*)d_ws;
  const size_t NELEM = (size_t)MROWS * EMB;            // 8388608
  unsigned short* xb    = ws;                          // reused as ctx
  unsigned short* wqkvT = xb + NELEM;                  // [6144][2048]; dead after gemm_qkv
  unsigned short* woutT = wqkvT + (size_t)NQKV * EMB;  // [2048][2048]
  unsigned short* Q     = woutT + (size_t)EMB * EMB;   // [32][2048][128]
  unsigned short* K     = Q + NELEM;
  unsigned short* Vt    = K + NELEM;                   // [32][128][2048]
  unsigned short* ctx   = xb;                          // alias: xb dead after gemm_qkv
  unsigned short* Opart = wqkvT;                       // alias: 512*16384 = 8.39M shorts
  float* Lp = (float*)(Opart + ((size_t)512 << 14));   // in wqkvT spare (12.58M region)

  // allow large dynamic LDS for the pipelined GEMMs (one-time host setup)
  static bool attr_done = false;
  if (!attr_done) {
    (void)hipFuncSetAttribute((const void*)gemm_qkv9,
                              hipFuncAttributeMaxDynamicSharedMemorySize, 131072);
    (void)hipFuncSetAttribute((const void*)gemm_out9,
                              hipFuncAttributeMaxDynamicSharedMemorySize, 98304);
    attr_done = true;
  }

  cast_bf16<<<8192, 256, 0, stream>>>(x, xb, (int)NELEM);
  transpose_cast<<<dim3(NQKV / 32, EMB / 32), dim3(32, 8), 0, stream>>>(wqkv, wqkvT, EMB, NQKV);
  transpose_cast<<<dim3(EMB / 32, EMB / 32), dim3(32, 8), 0, stream>>>(wout, woutT, EMB, EMB);
  gemm_qkv9<<<512, 512, 131072, stream>>>(xb, wqkvT, Q, K, Vt);
  attn<<<768, 256, 0, stream>>>(Q, K, Vt, ctx, Opart, Lp);
  attn_combine<<<2048, 256, 0, stream>>>(Opart, Lp, ctx);
  gemm_out9<<<256, 512, 98304, stream>>>(ctx, woutT, out);
}